// Round 6
// baseline (710.728 us; speedup 1.0000x reference)
//
#include <hip/hip_runtime.h>

#define BATCH 8
#define LFRM  6
#define NP    2048
#define MP    1024
#define CIN   64
#define MIDC  128
#define OUTC  256
#define TKM   384
#define KNN   32
#define RAD2  0.25f

#define FPS_BLOCKS (BATCH * LFRM)
#define FT_BLOCKS  (BATCH * LFRM * (NP / 64))

typedef float f2 __attribute__((ext_vector_type(2)));
typedef float f32x4 __attribute__((ext_vector_type(4)));
typedef _Float16 f16x8 __attribute__((ext_vector_type(8)));
typedef _Float16 f16x4 __attribute__((ext_vector_type(4)));

// LDS union: fps needs 32KB pts + winner slots + 12KB out-buffer (45.2KB);
// ftrans needs 51.7KB.
union SharedU {
  struct {
    float4 pts[NP];                    // 32 KB, [x,y,z,pad]
    unsigned long long wkey[2][4];     // parity-buffered wave keys
    float4 wcoord[2][4];               // winner coords per wave
    float wout[MP * 3];                // 12 KB: winners buffered in LDS
  } fps;                               //  -> ds_write only, so the per-iter
                                       //     barrier never drains vmcnt
  struct {
    float ftile[CIN][64];              // 16 KB
    float wfT[CIN][MIDC + 1];          // 33 KB
    float xt[64], yt[64], zt[64];      // point coords of this tile
    float wdl[MIDC * 3];               // w_d staged
  } ft;
};

__device__ __forceinline__ uint64_t kmax64(uint64_t a, uint64_t b) {
  return a > b ? a : b;
}
template <int CTRL>
__device__ __forceinline__ uint64_t key_dpp(uint64_t k) {
  int lo = __builtin_amdgcn_update_dpp((int)(uint32_t)k, (int)(uint32_t)k,
                                       CTRL, 0xF, 0xF, false);
  int hi = __builtin_amdgcn_update_dpp((int)(uint32_t)(k >> 32),
                                       (int)(uint32_t)(k >> 32),
                                       CTRL, 0xF, 0xF, false);
  return ((uint64_t)(uint32_t)hi << 32) | (uint32_t)lo;
}

// ---------------------------------------------------------------------------
// FPS: 4 waves, 2048 points register-resident (8 pts/lane, all named scalars).
// Key = (f32bits(dist) << 32) | ~pointidx; max-key == first-occurrence argmax
// (exact vs numpy; validated rounds 1-5). Winners go to LDS; one coalesced
// global dump at the end (keeps vmcnt out of the per-iteration barrier).
// ---------------------------------------------------------------------------
__device__ __forceinline__ void fps_path(const float* __restrict__ xyzs,
                                         float* __restrict__ out_xyz,
                                         SharedU* sh) {
#pragma clang fp contract(off)
  const int bt = blockIdx.x;              // b*6 + frame
  const int tid = threadIdx.x;
  const int lane = tid & 63, wv = tid >> 6;
  const float* src = xyzs + (size_t)bt * NP * 3;

  for (int q = tid; q < NP; q += 256)
    sh->fps.pts[q] = make_float4(src[q * 3 + 0], src[q * 3 + 1], src[q * 3 + 2], 0.f);
  __syncthreads();

  // wave wv owns slots [wv*8, wv*8+8); point p = slot*64 + lane
  const uint32_t base = (uint32_t)(((wv * 8) << 6) | lane);
  float4 A0 = sh->fps.pts[(wv * 8 + 0) * 64 + lane];
  float4 A1 = sh->fps.pts[(wv * 8 + 1) * 64 + lane];
  float4 A2 = sh->fps.pts[(wv * 8 + 2) * 64 + lane];
  float4 A3 = sh->fps.pts[(wv * 8 + 3) * 64 + lane];
  float4 A4 = sh->fps.pts[(wv * 8 + 4) * 64 + lane];
  float4 A5 = sh->fps.pts[(wv * 8 + 5) * 64 + lane];
  float4 A6 = sh->fps.pts[(wv * 8 + 6) * 64 + lane];
  float4 A7 = sh->fps.pts[(wv * 8 + 7) * 64 + lane];
  f2 px0 = {A0.x, A1.x}, py0 = {A0.y, A1.y}, pz0 = {A0.z, A1.z};
  f2 px1 = {A2.x, A3.x}, py1 = {A2.y, A3.y}, pz1 = {A2.z, A3.z};
  f2 px2 = {A4.x, A5.x}, py2 = {A4.y, A5.y}, pz2 = {A4.z, A5.z};
  f2 px3 = {A6.x, A7.x}, py3 = {A6.y, A7.y}, pz3 = {A6.z, A7.z};
  f2 d0 = {1e10f, 1e10f}, d1 = d0, d2 = d0, d3 = d0;

  float4 p0 = sh->fps.pts[0];
  float fx = p0.x, fy = p0.y, fz = p0.z;  // far = 0 initially

  for (int it = 0; it < MP; ++it) {
    if (tid == 0) {                       // emit current far point (LDS only)
      sh->fps.wout[it * 3 + 0] = fx;
      sh->fps.wout[it * 3 + 1] = fy;
      sh->fps.wout[it * 3 + 2] = fz;
    }
    const f2 fx2 = {fx, fx}, fy2 = {fy, fy}, fz2 = {fz, fz};
    f2 m, ddx, ddy, ddz;
    ddx = px0 - fx2; ddy = py0 - fy2; ddz = pz0 - fz2;
    m = ddx * ddx; m = m + ddy * ddy; m = m + ddz * ddz;   // contract off
    d0 = __builtin_elementwise_min(d0, m);
    ddx = px1 - fx2; ddy = py1 - fy2; ddz = pz1 - fz2;
    m = ddx * ddx; m = m + ddy * ddy; m = m + ddz * ddz;
    d1 = __builtin_elementwise_min(d1, m);
    ddx = px2 - fx2; ddy = py2 - fy2; ddz = pz2 - fz2;
    m = ddx * ddx; m = m + ddy * ddy; m = m + ddz * ddz;
    d2 = __builtin_elementwise_min(d2, m);
    ddx = px3 - fx2; ddy = py3 - fy2; ddz = pz3 - fz2;
    m = ddx * ddx; m = m + ddy * ddy; m = m + ddz * ddz;
    d3 = __builtin_elementwise_min(d3, m);

    // 8 candidate keys (named scalars only)
    const uint64_t k0 = ((uint64_t)__float_as_uint(d0.x) << 32) | (uint32_t)~(base + 0 * 64);
    const uint64_t k1 = ((uint64_t)__float_as_uint(d0.y) << 32) | (uint32_t)~(base + 1 * 64);
    const uint64_t k2 = ((uint64_t)__float_as_uint(d1.x) << 32) | (uint32_t)~(base + 2 * 64);
    const uint64_t k3 = ((uint64_t)__float_as_uint(d1.y) << 32) | (uint32_t)~(base + 3 * 64);
    const uint64_t k4 = ((uint64_t)__float_as_uint(d2.x) << 32) | (uint32_t)~(base + 4 * 64);
    const uint64_t k5 = ((uint64_t)__float_as_uint(d2.y) << 32) | (uint32_t)~(base + 5 * 64);
    const uint64_t k6 = ((uint64_t)__float_as_uint(d3.x) << 32) | (uint32_t)~(base + 6 * 64);
    const uint64_t k7 = ((uint64_t)__float_as_uint(d3.y) << 32) | (uint32_t)~(base + 7 * 64);

    // explicit 3-level tree: (max value, min index), coords carried
    bool s0 = k1 > k0; uint64_t e0 = s0 ? k1 : k0;
    float e0x = s0 ? px0.y : px0.x, e0y = s0 ? py0.y : py0.x, e0z = s0 ? pz0.y : pz0.x;
    bool s1 = k3 > k2; uint64_t e1 = s1 ? k3 : k2;
    float e1x = s1 ? px1.y : px1.x, e1y = s1 ? py1.y : py1.x, e1z = s1 ? pz1.y : pz1.x;
    bool s2 = k5 > k4; uint64_t e2 = s2 ? k5 : k4;
    float e2x = s2 ? px2.y : px2.x, e2y = s2 ? py2.y : py2.x, e2z = s2 ? pz2.y : pz2.x;
    bool s3 = k7 > k6; uint64_t e3 = s3 ? k7 : k6;
    float e3x = s3 ? px3.y : px3.x, e3y = s3 ? py3.y : py3.x, e3z = s3 ? pz3.y : pz3.x;
    bool t0 = e1 > e0; uint64_t g0 = t0 ? e1 : e0;
    float g0x = t0 ? e1x : e0x, g0y = t0 ? e1y : e0y, g0z = t0 ? e1z : e0z;
    bool t1 = e3 > e2; uint64_t g1 = t1 ? e3 : e2;
    float g1x = t1 ? e3x : e2x, g1y = t1 ? e3y : e2y, g1z = t1 ? e3z : e2z;
    bool v0 = g1 > g0; const uint64_t kl = v0 ? g1 : g0;
    const float blx = v0 ? g1x : g0x, bly = v0 ? g1y : g0y, blz = v0 ? g1z : g0z;

    // wave max via DPP only (no LDS): ror 1,2,4,8 then bcast15, bcast31
    uint64_t kr = kl;
    kr = kmax64(kr, key_dpp<0x121>(kr));  // row_ror:1
    kr = kmax64(kr, key_dpp<0x122>(kr));  // row_ror:2
    kr = kmax64(kr, key_dpp<0x124>(kr));  // row_ror:4
    kr = kmax64(kr, key_dpp<0x128>(kr));  // row_ror:8  -> row max in all 16
    kr = kmax64(kr, key_dpp<0x142>(kr));  // row_bcast15: rows 1,3 absorb 0,2
    kr = kmax64(kr, key_dpp<0x143>(kr));  // row_bcast31: lane63 = wave max
    const uint32_t rlo = (uint32_t)__builtin_amdgcn_readlane((int)(uint32_t)kr, 63);
    const uint32_t rhi = (uint32_t)__builtin_amdgcn_readlane((int)(uint32_t)(kr >> 32), 63);
    const uint64_t skr = ((uint64_t)rhi << 32) | rlo;

    const int par = it & 1;
    if (kl == skr) {                      // unique winner lane of this wave
      sh->fps.wkey[par][wv] = kl;
      sh->fps.wcoord[par][wv] = make_float4(blx, bly, blz, 0.f);
    }
    __syncthreads();
    uint64_t q0 = sh->fps.wkey[par][0], q1 = sh->fps.wkey[par][1];
    uint64_t q2 = sh->fps.wkey[par][2], q3 = sh->fps.wkey[par][3];
    float4 c0 = sh->fps.wcoord[par][0], c1 = sh->fps.wcoord[par][1];
    float4 c2 = sh->fps.wcoord[par][2], c3 = sh->fps.wcoord[par][3];
    bool ca = q1 > q0; uint64_t ka = ca ? q1 : q0; float4 va = ca ? c1 : c0;
    bool cb = q3 > q2; uint64_t kb = cb ? q3 : q2; float4 vb = cb ? c3 : c2;
    bool cc = kb > ka; float4 vw = cc ? vb : va;
    fx = vw.x; fy = vw.y; fz = vw.z;
  }

  // one coalesced dump of all winners
  __syncthreads();
  float* dst = out_xyz + (size_t)bt * MP * 3;
  for (int q = tid; q < MP * 3; q += 256) dst[q] = sh->fps.wout[q];
}

// ---------------------------------------------------------------------------
// ftrans: G[b,l,n,o] = sum_c w_f[o,c]*features[b,l,c,n] + w_d[o]·xyz[b,l,n]
// ---------------------------------------------------------------------------
__device__ __forceinline__ void ftrans_path(const float* __restrict__ features,
                                            const float* __restrict__ w_f,
                                            const float* __restrict__ w_d,
                                            const float* __restrict__ xyzs,
                                            float* __restrict__ G,
                                            SharedU* sh) {
  const int blk = blockIdx.x - FPS_BLOCKS;
  const int ntile = blk & 31;             // N/64 tiles
  const int bl = blk >> 5;                // b*L + l
  const int tid = threadIdx.x;

  const float* fsrc = features + (size_t)bl * CIN * NP + (size_t)ntile * 64;
  for (int idx = tid; idx < CIN * 64; idx += 256) {
    int c = idx >> 6, n = idx & 63;
    sh->ft.ftile[c][n] = fsrc[(size_t)c * NP + n];
  }
  for (int idx = tid; idx < CIN * MIDC; idx += 256) {
    int c = idx & 63, o = idx >> 6;       // coalesced w_f row reads
    sh->ft.wfT[c][o] = w_f[o * CIN + c];
  }
  if (tid < 64) {
    const float* xs = xyzs + ((size_t)bl * NP + (size_t)ntile * 64 + tid) * 3;
    sh->ft.xt[tid] = xs[0];
    sh->ft.yt[tid] = xs[1];
    sh->ft.zt[tid] = xs[2];
  }
  for (int idx = tid; idx < MIDC * 3; idx += 256) sh->ft.wdl[idx] = w_d[idx];
  __syncthreads();

  const int o = tid & 127, nh = tid >> 7;
  const float wd0 = sh->ft.wdl[o * 3 + 0];
  const float wd1 = sh->ft.wdl[o * 3 + 1];
  const float wd2 = sh->ft.wdl[o * 3 + 2];
  float* dst = G + ((size_t)bl * NP + (size_t)ntile * 64) * MIDC;
  for (int q = 0; q < 32; ++q) {
    int n = nh * 32 + q;
    float acc = wd0 * sh->ft.xt[n] + wd1 * sh->ft.yt[n] + wd2 * sh->ft.zt[n];
#pragma unroll 16
    for (int c = 0; c < CIN; ++c) acc += sh->ft.wfT[c][o] * sh->ft.ftile[c][n];
    dst[(size_t)n * MIDC + o] = acc;
  }
}

__global__ __launch_bounds__(256, 1) void fps_ftrans_kernel(
    const float* __restrict__ xyzs, const float* __restrict__ features,
    const float* __restrict__ w_f, const float* __restrict__ w_d,
    float* __restrict__ out_xyz, float* __restrict__ G) {
  __shared__ SharedU sh;
  if (blockIdx.x < FPS_BLOCKS) {
    fps_path(xyzs, out_xyz, &sh);
    return;
  }
  ftrans_path(features, w_f, w_d, xyzs, G, &sh);
}

// ---------------------------------------------------------------------------
// pst_main: ball query + gathered max-pool of G + fp16 MFMA w_t GEMM.
// (unchanged: measured ~123-153 us)
// ---------------------------------------------------------------------------
#define PSTR 392   // fp16 K-stride: 2-way banks on B-frag ds_read_b128

__global__ __launch_bounds__(256) void pst_main(const float* __restrict__ xyzs,
                                                const float* __restrict__ w_d,
                                                const float* __restrict__ w_t,
                                                const float* __restrict__ G,
                                                const float* __restrict__ anchors,
                                                float* __restrict__ out_feat) {
  __shared__ float pxyz[NP * 3];              // 24 KB frame xyz
  __shared__ _Float16 sfp16[32][PSTR];        // 24.5 KB sf (all 3 slices), fp16
  __shared__ unsigned short nidx[32][KNN];    // 2 KB
  __shared__ float anc[32][3];

  const int blk = blockIdx.x;
  const int mt = blk & 31;                // M/32 tiles
  const int bt = blk >> 5;                // b*6 + (t-1)
  const int b = bt / LFRM;
  const int t = bt % LFRM + 1;            // padded time index, 1..6
  const int tid = threadIdx.x;

  const float* asrc = anchors + ((size_t)bt * MP + (size_t)mt * 32) * 3;
  if (tid < 96) anc[tid / 3][tid % 3] = asrc[tid];
  __syncthreads();

  const int al = tid >> 3;                // anchor 0..31
  const int j = tid & 7;                  // 0..7 within anchor group
  const float ax = anc[al][0], ay = anc[al][1], az = anc[al][2];

  float wda[16];
#pragma unroll
  for (int c4 = 0; c4 < 4; ++c4)
#pragma unroll
    for (int r = 0; r < 4; ++r) {
      int o = c4 * 32 + j * 4 + r;
      wda[c4 * 4 + r] = w_d[o * 3 + 0] * ax + w_d[o * 3 + 1] * ay +
                        w_d[o * 3 + 2] * az;
    }

  const int lane = tid & 63, wv = tid >> 6;

  for (int ii = 0; ii < 3; ++ii) {
    const int i = t - 1 + ii;             // padded frame 0..7
    float mg[16];
#pragma unroll
    for (int u = 0; u < 16; ++u) mg[u] = 0.f;   // pad frame: maxG := 0

    if (i != 0 && i != LFRM + 1) {
      const int f2i = i - 1;
      const float* fxyz = xyzs + (size_t)(b * LFRM + f2i) * NP * 3;
      __syncthreads();                    // prior ball-query reads done
      for (int q = tid; q < NP * 3; q += 256) pxyz[q] = fxyz[q];
      __syncthreads();

      // ---- ball query: first KNN in-radius indices, in index order ----
      for (int aa = 0; aa < 8; ++aa) {
        const int a = wv * 8 + aa;
        const float qx = anc[a][0], qy = anc[a][1], qz = anc[a][2];
        int total = 0;
        int fillidx = 0;
        for (int ch = 0; ch < NP / 64; ++ch) {
          const int p = ch * 64 + lane;
          float d2;
          {
#pragma clang fp contract(off)
            float dx = qx - pxyz[p * 3 + 0];
            float dy = qy - pxyz[p * 3 + 1];
            float dz = qz - pxyz[p * 3 + 2];
            d2 = dx * dx + dy * dy + dz * dz;
          }
          const bool inb = d2 < RAD2;
          const unsigned long long mk = __ballot(inb);
          if (mk != 0ull && total == 0)
            fillidx = ch * 64 + (int)__builtin_ctzll(mk);
          const int before = (int)__builtin_popcountll(mk & ((1ull << lane) - 1ull));
          const int slot = total + before;
          if (inb && slot < KNN) nidx[a][slot] = (unsigned short)p;
          total += (int)__builtin_popcountll(mk);
          if (total >= KNN) break;        // uniform across wave
        }
        const int nf = total < KNN ? total : KNN;
        if (lane < KNN - nf) nidx[a][nf + lane] = (unsigned short)fillidx;
      }
      __syncthreads();

      // ---- mid: pure max over gathered G rows ----
      const float* gf = G + (size_t)(b * LFRM + f2i) * NP * MIDC;
#pragma unroll
      for (int u = 0; u < 16; ++u) mg[u] = -1e30f;
      for (int k = 0; k < KNN; ++k) {
        const int p = nidx[al][k];
        const float4* row = (const float4*)(gf + (size_t)p * MIDC);
#pragma unroll
        for (int c4 = 0; c4 < 4; ++c4) {
          float4 v = row[c4 * 8 + j];
          mg[c4 * 4 + 0] = fmaxf(mg[c4 * 4 + 0], v.x);
          mg[c4 * 4 + 1] = fmaxf(mg[c4 * 4 + 1], v.y);
          mg[c4 * 4 + 2] = fmaxf(mg[c4 * 4 + 2], v.z);
          mg[c4 * 4 + 3] = fmaxf(mg[c4 * 4 + 3], v.w);
        }
      }
    }

    // sf = relu(maxG - wda) -> fp16, packed 4-wide writes
#pragma unroll
    for (int c4 = 0; c4 < 4; ++c4) {
      f16x4 h;
#pragma unroll
      for (int r = 0; r < 4; ++r)
        h[r] = (_Float16)fmaxf(mg[c4 * 4 + r] - wda[c4 * 4 + r], 0.f);
      *(f16x4*)&sfp16[al][ii * MIDC + c4 * 32 + j * 4] = h;
    }
  }
  __syncthreads();

  // ---- GEMM: wave wv owns M-tiles wv*4..wv*4+3 (out-ch), N-tiles 0..1 ----
  const int l16 = lane & 15, lq = lane >> 4;
  f32x4 accm[4][2];
#pragma unroll
  for (int q = 0; q < 4; ++q)
#pragma unroll
    for (int n2 = 0; n2 < 2; ++n2) accm[q][n2] = f32x4{0.f, 0.f, 0.f, 0.f};

  for (int kc = 0; kc < TKM / 32; ++kc) {
    f16x8 bfr[2];
#pragma unroll
    for (int n2 = 0; n2 < 2; ++n2)
      bfr[n2] = *(const f16x8*)&sfp16[n2 * 16 + l16][kc * 32 + lq * 8];
#pragma unroll
    for (int q = 0; q < 4; ++q) {
      const int row = (wv * 4 + q) * 16 + l16;
      const float4* ap = (const float4*)(w_t + (size_t)row * TKM + kc * 32 + lq * 8);
      float4 a0 = ap[0], a1 = ap[1];
      f16x8 afr;
      afr[0] = (_Float16)a0.x; afr[1] = (_Float16)a0.y;
      afr[2] = (_Float16)a0.z; afr[3] = (_Float16)a0.w;
      afr[4] = (_Float16)a1.x; afr[5] = (_Float16)a1.y;
      afr[6] = (_Float16)a1.z; afr[7] = (_Float16)a1.w;
      accm[q][0] = __builtin_amdgcn_mfma_f32_16x16x32_f16(afr, bfr[0], accm[q][0], 0, 0, 0);
      accm[q][1] = __builtin_amdgcn_mfma_f32_16x16x32_f16(afr, bfr[1], accm[q][1], 0, 0, 0);
    }
  }

  // epilogue: D row = out-ch offset lq*4+r, col = anchor l16 (m89 layout)
  float* ob = out_feat + (size_t)bt * OUTC * MP + (size_t)mt * 32;
#pragma unroll
  for (int q = 0; q < 4; ++q) {
    const int orow = (wv * 4 + q) * 16 + lq * 4;
#pragma unroll
    for (int n2 = 0; n2 < 2; ++n2)
#pragma unroll
      for (int r = 0; r < 4; ++r)
        ob[(size_t)(orow + r) * MP + n2 * 16 + l16] = accm[q][n2][r];
  }
}

// ---------------------------------------------------------------------------
extern "C" void kernel_launch(void* const* d_in, const int* in_sizes, int n_in,
                              void* d_out, int out_size, void* d_ws, size_t ws_size,
                              hipStream_t stream) {
  const float* xyzs = (const float*)d_in[0];
  const float* features = (const float*)d_in[1];
  const float* w_d = (const float*)d_in[2];
  const float* w_f = (const float*)d_in[3];
  const float* w_t = (const float*)d_in[4];

  float* out = (float*)d_out;
  float* out_xyz = out;                                        // (B,6,M,3)
  float* out_feat = out + (size_t)BATCH * LFRM * MP * 3;       // (B,6,256,M)
  float* G = (float*)d_ws;                                     // (B,L,N,128)

  hipLaunchKernelGGL(fps_ftrans_kernel, dim3(FPS_BLOCKS + FT_BLOCKS), dim3(256),
                     0, stream, xyzs, features, w_f, w_d, out_xyz, G);
  hipLaunchKernelGGL(pst_main, dim3(BATCH * LFRM * (MP / 32)), dim3(256), 0,
                     stream, xyzs, w_d, w_t, G, out_xyz, out_feat);
}

// Round 7
// 690.907 us; speedup vs baseline: 1.0287x; 1.0287x over previous
//
#include <hip/hip_runtime.h>

#define BATCH 8
#define LFRM  6
#define NP    2048
#define MP    1024
#define CIN   64
#define MIDC  128
#define OUTC  256
#define TKM   384
#define KNN   32
#define RAD2  0.25f

#define FPS_BLOCKS (BATCH * LFRM)
#define FT_BLOCKS  (BATCH * LFRM * (NP / 64))

typedef float f2 __attribute__((ext_vector_type(2)));
typedef float f32x4 __attribute__((ext_vector_type(4)));
typedef _Float16 f16x8 __attribute__((ext_vector_type(8)));
typedef _Float16 f16x4 __attribute__((ext_vector_type(4)));

// LDS union: fps needs 32K pts + 12K wout + slots; ftrans needs 51.7KB.
union SharedU {
  struct {
    float4 pts[NP];                    // 32 KB, [x,y,z,pad]
    unsigned long long wkey[2][4];     // parity-buffered wave keys
    float4 wcoord[2][4];               // winner coords per wave
    float wout[MP * 3];                // 12 KB: winners buffered in LDS
  } fps;
  struct {
    float ftile[CIN][64];              // 16 KB
    float wfT[CIN][MIDC + 1];          // 33 KB
    float xt[64], yt[64], zt[64];      // point coords of this tile
    float wdl[MIDC * 3];               // w_d staged
  } ft;
};

template <int CTRL>
__device__ __forceinline__ float fmax_dpp(float v) {
  int t = __builtin_amdgcn_update_dpp(__float_as_int(v), __float_as_int(v),
                                      CTRL, 0xF, 0xF, false);
  return fmaxf(v, __int_as_float(t));
}
template <int CTRL>
__device__ __forceinline__ uint32_t umin_dpp(uint32_t v) {
  uint32_t t = (uint32_t)__builtin_amdgcn_update_dpp((int)v, (int)v,
                                                     CTRL, 0xF, 0xF, false);
  return v < t ? v : t;
}

// ---------------------------------------------------------------------------
// FPS: 4 waves, 2048 points register-resident (8 pts/lane, named scalars).
// VALU-issue-bound (r6 post-mortem) -> minimal-instruction iteration:
//   value reduce in f32 (packed max tree + 6 DPP v_max_f32),
//   index  reduce via equality-select + 6 DPP v_min_u32 (= first-occurrence
//   argmax: smallest point index among max-achievers; exact for dist>=0),
//   winner wave pre-reads pts[wp] BEFORE the barrier and publishes key+coords.
// Semantics identical to the u64-key scheme validated in rounds 1-6.
// ---------------------------------------------------------------------------
__device__ __forceinline__ void fps_path(const float* __restrict__ xyzs,
                                         float* __restrict__ out_xyz,
                                         SharedU* sh) {
#pragma clang fp contract(off)
  const int bt = blockIdx.x;              // b*6 + frame
  const int tid = threadIdx.x;
  const int lane = tid & 63, wv = tid >> 6;
  const float* src = xyzs + (size_t)bt * NP * 3;

  for (int q = tid; q < NP; q += 256)
    sh->fps.pts[q] = make_float4(src[q * 3 + 0], src[q * 3 + 1], src[q * 3 + 2], 0.f);
  __syncthreads();

  // wave wv owns slots [wv*8, wv*8+8); point p = slot*64 + lane
  const uint32_t base = (uint32_t)(((wv * 8) << 6) | lane);
  const uint32_t p0c = base + 0 * 64, p1c = base + 1 * 64;
  const uint32_t p2c = base + 2 * 64, p3c = base + 3 * 64;
  const uint32_t p4c = base + 4 * 64, p5c = base + 5 * 64;
  const uint32_t p6c = base + 6 * 64, p7c = base + 7 * 64;

  float4 A0 = sh->fps.pts[(wv * 8 + 0) * 64 + lane];
  float4 A1 = sh->fps.pts[(wv * 8 + 1) * 64 + lane];
  float4 A2 = sh->fps.pts[(wv * 8 + 2) * 64 + lane];
  float4 A3 = sh->fps.pts[(wv * 8 + 3) * 64 + lane];
  float4 A4 = sh->fps.pts[(wv * 8 + 4) * 64 + lane];
  float4 A5 = sh->fps.pts[(wv * 8 + 5) * 64 + lane];
  float4 A6 = sh->fps.pts[(wv * 8 + 6) * 64 + lane];
  float4 A7 = sh->fps.pts[(wv * 8 + 7) * 64 + lane];
  f2 px0 = {A0.x, A1.x}, py0 = {A0.y, A1.y}, pz0 = {A0.z, A1.z};
  f2 px1 = {A2.x, A3.x}, py1 = {A2.y, A3.y}, pz1 = {A2.z, A3.z};
  f2 px2 = {A4.x, A5.x}, py2 = {A4.y, A5.y}, pz2 = {A4.z, A5.z};
  f2 px3 = {A6.x, A7.x}, py3 = {A6.y, A7.y}, pz3 = {A6.z, A7.z};
  f2 d0 = {1e10f, 1e10f}, d1 = d0, d2 = d0, d3 = d0;

  float4 p0 = sh->fps.pts[0];
  float fx = p0.x, fy = p0.y, fz = p0.z;  // far = 0 initially

  for (int it = 0; it < MP; ++it) {
    if (tid == 0) {                       // emit current far point (LDS only)
      sh->fps.wout[it * 3 + 0] = fx;
      sh->fps.wout[it * 3 + 1] = fy;
      sh->fps.wout[it * 3 + 2] = fz;
    }
    const f2 fx2 = {fx, fx}, fy2 = {fy, fy}, fz2 = {fz, fz};
    f2 m, ddx, ddy, ddz;
    ddx = px0 - fx2; ddy = py0 - fy2; ddz = pz0 - fz2;
    m = ddx * ddx; m = m + ddy * ddy; m = m + ddz * ddz;   // contract off
    d0 = __builtin_elementwise_min(d0, m);
    ddx = px1 - fx2; ddy = py1 - fy2; ddz = pz1 - fz2;
    m = ddx * ddx; m = m + ddy * ddy; m = m + ddz * ddz;
    d1 = __builtin_elementwise_min(d1, m);
    ddx = px2 - fx2; ddy = py2 - fy2; ddz = pz2 - fz2;
    m = ddx * ddx; m = m + ddy * ddy; m = m + ddz * ddz;
    d2 = __builtin_elementwise_min(d2, m);
    ddx = px3 - fx2; ddy = py3 - fy2; ddz = pz3 - fz2;
    m = ddx * ddx; m = m + ddy * ddy; m = m + ddz * ddz;
    d3 = __builtin_elementwise_min(d3, m);

    // per-lane max value (packed tree), then wave max via 6 DPP f32 max
    f2 m01 = __builtin_elementwise_max(d0, d1);
    f2 m23 = __builtin_elementwise_max(d2, d3);
    f2 mA = __builtin_elementwise_max(m01, m23);
    float bv = fmaxf(mA.x, mA.y);
    bv = fmax_dpp<0x121>(bv);             // row_ror:1
    bv = fmax_dpp<0x122>(bv);             // row_ror:2
    bv = fmax_dpp<0x124>(bv);             // row_ror:4
    bv = fmax_dpp<0x128>(bv);             // row_ror:8
    bv = fmax_dpp<0x142>(bv);             // row_bcast15
    bv = fmax_dpp<0x143>(bv);             // row_bcast31: lane63 = wave max
    const float wm = __int_as_float(__builtin_amdgcn_readlane(__float_as_int(bv), 63));

    // smallest point index achieving wm (s descending -> first match wins)
    uint32_t cand = 0xFFFFFFFFu;
    cand = (d3.y == wm) ? p7c : cand;
    cand = (d3.x == wm) ? p6c : cand;
    cand = (d2.y == wm) ? p5c : cand;
    cand = (d2.x == wm) ? p4c : cand;
    cand = (d1.y == wm) ? p3c : cand;
    cand = (d1.x == wm) ? p2c : cand;
    cand = (d0.y == wm) ? p1c : cand;
    cand = (d0.x == wm) ? p0c : cand;
    cand = umin_dpp<0x121>(cand);
    cand = umin_dpp<0x122>(cand);
    cand = umin_dpp<0x124>(cand);
    cand = umin_dpp<0x128>(cand);
    cand = umin_dpp<0x142>(cand);
    cand = umin_dpp<0x143>(cand);         // lane63 = wave argmax index
    const uint32_t wp = (uint32_t)__builtin_amdgcn_readlane((int)cand, 63);

    // wave winner: pre-read coords (overlaps publish; before barrier),
    // publish u64 key = (distbits<<32) | ~idx  (max-key == max dist, min idx)
    const uint64_t kw = ((uint64_t)(uint32_t)__float_as_uint(wm) << 32) |
                        (uint32_t)(~wp);
    float4 wc = sh->fps.pts[wp];          // uniform -> broadcast read
    const int par = it & 1;
    if (lane == 0) {
      sh->fps.wkey[par][wv] = kw;
      sh->fps.wcoord[par][wv] = wc;
    }
    __syncthreads();

    uint64_t q0 = sh->fps.wkey[par][0], q1 = sh->fps.wkey[par][1];
    uint64_t q2 = sh->fps.wkey[par][2], q3 = sh->fps.wkey[par][3];
    float4 c0 = sh->fps.wcoord[par][0], c1 = sh->fps.wcoord[par][1];
    float4 c2 = sh->fps.wcoord[par][2], c3 = sh->fps.wcoord[par][3];
    bool ca = q1 > q0; uint64_t ka = ca ? q1 : q0; float4 va = ca ? c1 : c0;
    bool cb = q3 > q2; uint64_t kb = cb ? q3 : q2; float4 vb = cb ? c3 : c2;
    bool cc = kb > ka; float4 vw = cc ? vb : va;
    fx = vw.x; fy = vw.y; fz = vw.z;
  }

  // one coalesced dump of all winners
  __syncthreads();
  float* dst = out_xyz + (size_t)bt * MP * 3;
  for (int q = tid; q < MP * 3; q += 256) dst[q] = sh->fps.wout[q];
}

// ---------------------------------------------------------------------------
// ftrans: G[b,l,n,o] = sum_c w_f[o,c]*features[b,l,c,n] + w_d[o]·xyz[b,l,n]
// ---------------------------------------------------------------------------
__device__ __forceinline__ void ftrans_path(const float* __restrict__ features,
                                            const float* __restrict__ w_f,
                                            const float* __restrict__ w_d,
                                            const float* __restrict__ xyzs,
                                            float* __restrict__ G,
                                            SharedU* sh) {
  const int blk = blockIdx.x - FPS_BLOCKS;
  const int ntile = blk & 31;             // N/64 tiles
  const int bl = blk >> 5;                // b*L + l
  const int tid = threadIdx.x;

  const float* fsrc = features + (size_t)bl * CIN * NP + (size_t)ntile * 64;
  for (int idx = tid; idx < CIN * 64; idx += 256) {
    int c = idx >> 6, n = idx & 63;
    sh->ft.ftile[c][n] = fsrc[(size_t)c * NP + n];
  }
  for (int idx = tid; idx < CIN * MIDC; idx += 256) {
    int c = idx & 63, o = idx >> 6;       // coalesced w_f row reads
    sh->ft.wfT[c][o] = w_f[o * CIN + c];
  }
  if (tid < 64) {
    const float* xs = xyzs + ((size_t)bl * NP + (size_t)ntile * 64 + tid) * 3;
    sh->ft.xt[tid] = xs[0];
    sh->ft.yt[tid] = xs[1];
    sh->ft.zt[tid] = xs[2];
  }
  for (int idx = tid; idx < MIDC * 3; idx += 256) sh->ft.wdl[idx] = w_d[idx];
  __syncthreads();

  const int o = tid & 127, nh = tid >> 7;
  const float wd0 = sh->ft.wdl[o * 3 + 0];
  const float wd1 = sh->ft.wdl[o * 3 + 1];
  const float wd2 = sh->ft.wdl[o * 3 + 2];
  float* dst = G + ((size_t)bl * NP + (size_t)ntile * 64) * MIDC;
  for (int q = 0; q < 32; ++q) {
    int n = nh * 32 + q;
    float acc = wd0 * sh->ft.xt[n] + wd1 * sh->ft.yt[n] + wd2 * sh->ft.zt[n];
#pragma unroll 16
    for (int c = 0; c < CIN; ++c) acc += sh->ft.wfT[c][o] * sh->ft.ftile[c][n];
    dst[(size_t)n * MIDC + o] = acc;
  }
}

__global__ __launch_bounds__(256, 1) void fps_ftrans_kernel(
    const float* __restrict__ xyzs, const float* __restrict__ features,
    const float* __restrict__ w_f, const float* __restrict__ w_d,
    float* __restrict__ out_xyz, float* __restrict__ G) {
  __shared__ SharedU sh;
  if (blockIdx.x < FPS_BLOCKS) {
    fps_path(xyzs, out_xyz, &sh);
    return;
  }
  ftrans_path(features, w_f, w_d, xyzs, G, &sh);
}

// ---------------------------------------------------------------------------
// pst_main: ball query + gathered max-pool of G + fp16 MFMA w_t GEMM.
// (unchanged: measured ~123-153 us)
// ---------------------------------------------------------------------------
#define PSTR 392   // fp16 K-stride: 2-way banks on B-frag ds_read_b128

__global__ __launch_bounds__(256) void pst_main(const float* __restrict__ xyzs,
                                                const float* __restrict__ w_d,
                                                const float* __restrict__ w_t,
                                                const float* __restrict__ G,
                                                const float* __restrict__ anchors,
                                                float* __restrict__ out_feat) {
  __shared__ float pxyz[NP * 3];              // 24 KB frame xyz
  __shared__ _Float16 sfp16[32][PSTR];        // 24.5 KB sf (all 3 slices), fp16
  __shared__ unsigned short nidx[32][KNN];    // 2 KB
  __shared__ float anc[32][3];

  const int blk = blockIdx.x;
  const int mt = blk & 31;                // M/32 tiles
  const int bt = blk >> 5;                // b*6 + (t-1)
  const int b = bt / LFRM;
  const int t = bt % LFRM + 1;            // padded time index, 1..6
  const int tid = threadIdx.x;

  const float* asrc = anchors + ((size_t)bt * MP + (size_t)mt * 32) * 3;
  if (tid < 96) anc[tid / 3][tid % 3] = asrc[tid];
  __syncthreads();

  const int al = tid >> 3;                // anchor 0..31
  const int j = tid & 7;                  // 0..7 within anchor group
  const float ax = anc[al][0], ay = anc[al][1], az = anc[al][2];

  float wda[16];
#pragma unroll
  for (int c4 = 0; c4 < 4; ++c4)
#pragma unroll
    for (int r = 0; r < 4; ++r) {
      int o = c4 * 32 + j * 4 + r;
      wda[c4 * 4 + r] = w_d[o * 3 + 0] * ax + w_d[o * 3 + 1] * ay +
                        w_d[o * 3 + 2] * az;
    }

  const int lane = tid & 63, wv = tid >> 6;

  for (int ii = 0; ii < 3; ++ii) {
    const int i = t - 1 + ii;             // padded frame 0..7
    float mg[16];
#pragma unroll
    for (int u = 0; u < 16; ++u) mg[u] = 0.f;   // pad frame: maxG := 0

    if (i != 0 && i != LFRM + 1) {
      const int f2i = i - 1;
      const float* fxyz = xyzs + (size_t)(b * LFRM + f2i) * NP * 3;
      __syncthreads();                    // prior ball-query reads done
      for (int q = tid; q < NP * 3; q += 256) pxyz[q] = fxyz[q];
      __syncthreads();

      // ---- ball query: first KNN in-radius indices, in index order ----
      for (int aa = 0; aa < 8; ++aa) {
        const int a = wv * 8 + aa;
        const float qx = anc[a][0], qy = anc[a][1], qz = anc[a][2];
        int total = 0;
        int fillidx = 0;
        for (int ch = 0; ch < NP / 64; ++ch) {
          const int p = ch * 64 + lane;
          float d2;
          {
#pragma clang fp contract(off)
            float dx = qx - pxyz[p * 3 + 0];
            float dy = qy - pxyz[p * 3 + 1];
            float dz = qz - pxyz[p * 3 + 2];
            d2 = dx * dx + dy * dy + dz * dz;
          }
          const bool inb = d2 < RAD2;
          const unsigned long long mk = __ballot(inb);
          if (mk != 0ull && total == 0)
            fillidx = ch * 64 + (int)__builtin_ctzll(mk);
          const int before = (int)__builtin_popcountll(mk & ((1ull << lane) - 1ull));
          const int slot = total + before;
          if (inb && slot < KNN) nidx[a][slot] = (unsigned short)p;
          total += (int)__builtin_popcountll(mk);
          if (total >= KNN) break;        // uniform across wave
        }
        const int nf = total < KNN ? total : KNN;
        if (lane < KNN - nf) nidx[a][nf + lane] = (unsigned short)fillidx;
      }
      __syncthreads();

      // ---- mid: pure max over gathered G rows ----
      const float* gf = G + (size_t)(b * LFRM + f2i) * NP * MIDC;
#pragma unroll
      for (int u = 0; u < 16; ++u) mg[u] = -1e30f;
      for (int k = 0; k < KNN; ++k) {
        const int p = nidx[al][k];
        const float4* row = (const float4*)(gf + (size_t)p * MIDC);
#pragma unroll
        for (int c4 = 0; c4 < 4; ++c4) {
          float4 v = row[c4 * 8 + j];
          mg[c4 * 4 + 0] = fmaxf(mg[c4 * 4 + 0], v.x);
          mg[c4 * 4 + 1] = fmaxf(mg[c4 * 4 + 1], v.y);
          mg[c4 * 4 + 2] = fmaxf(mg[c4 * 4 + 2], v.z);
          mg[c4 * 4 + 3] = fmaxf(mg[c4 * 4 + 3], v.w);
        }
      }
    }

    // sf = relu(maxG - wda) -> fp16, packed 4-wide writes
#pragma unroll
    for (int c4 = 0; c4 < 4; ++c4) {
      f16x4 h;
#pragma unroll
      for (int r = 0; r < 4; ++r)
        h[r] = (_Float16)fmaxf(mg[c4 * 4 + r] - wda[c4 * 4 + r], 0.f);
      *(f16x4*)&sfp16[al][ii * MIDC + c4 * 32 + j * 4] = h;
    }
  }
  __syncthreads();

  // ---- GEMM: wave wv owns M-tiles wv*4..wv*4+3 (out-ch), N-tiles 0..1 ----
  const int l16 = lane & 15, lq = lane >> 4;
  f32x4 accm[4][2];
#pragma unroll
  for (int q = 0; q < 4; ++q)
#pragma unroll
    for (int n2 = 0; n2 < 2; ++n2) accm[q][n2] = f32x4{0.f, 0.f, 0.f, 0.f};

  for (int kc = 0; kc < TKM / 32; ++kc) {
    f16x8 bfr[2];
#pragma unroll
    for (int n2 = 0; n2 < 2; ++n2)
      bfr[n2] = *(const f16x8*)&sfp16[n2 * 16 + l16][kc * 32 + lq * 8];
#pragma unroll
    for (int q = 0; q < 4; ++q) {
      const int row = (wv * 4 + q) * 16 + l16;
      const float4* ap = (const float4*)(w_t + (size_t)row * TKM + kc * 32 + lq * 8);
      float4 a0 = ap[0], a1 = ap[1];
      f16x8 afr;
      afr[0] = (_Float16)a0.x; afr[1] = (_Float16)a0.y;
      afr[2] = (_Float16)a0.z; afr[3] = (_Float16)a0.w;
      afr[4] = (_Float16)a1.x; afr[5] = (_Float16)a1.y;
      afr[6] = (_Float16)a1.z; afr[7] = (_Float16)a1.w;
      accm[q][0] = __builtin_amdgcn_mfma_f32_16x16x32_f16(afr, bfr[0], accm[q][0], 0, 0, 0);
      accm[q][1] = __builtin_amdgcn_mfma_f32_16x16x32_f16(afr, bfr[1], accm[q][1], 0, 0, 0);
    }
  }

  // epilogue: D row = out-ch offset lq*4+r, col = anchor l16 (m89 layout)
  float* ob = out_feat + (size_t)bt * OUTC * MP + (size_t)mt * 32;
#pragma unroll
  for (int q = 0; q < 4; ++q) {
    const int orow = (wv * 4 + q) * 16 + lq * 4;
#pragma unroll
    for (int n2 = 0; n2 < 2; ++n2)
#pragma unroll
      for (int r = 0; r < 4; ++r)
        ob[(size_t)(orow + r) * MP + n2 * 16 + l16] = accm[q][n2][r];
  }
}

// ---------------------------------------------------------------------------
extern "C" void kernel_launch(void* const* d_in, const int* in_sizes, int n_in,
                              void* d_out, int out_size, void* d_ws, size_t ws_size,
                              hipStream_t stream) {
  const float* xyzs = (const float*)d_in[0];
  const float* features = (const float*)d_in[1];
  const float* w_d = (const float*)d_in[2];
  const float* w_f = (const float*)d_in[3];
  const float* w_t = (const float*)d_in[4];

  float* out = (float*)d_out;
  float* out_xyz = out;                                        // (B,6,M,3)
  float* out_feat = out + (size_t)BATCH * LFRM * MP * 3;       // (B,6,256,M)
  float* G = (float*)d_ws;                                     // (B,L,N,128)

  hipLaunchKernelGGL(fps_ftrans_kernel, dim3(FPS_BLOCKS + FT_BLOCKS), dim3(256),
                     0, stream, xyzs, features, w_f, w_d, out_xyz, G);
  hipLaunchKernelGGL(pst_main, dim3(BATCH * LFRM * (MP / 32)), dim3(256), 0,
                     stream, xyzs, w_d, w_t, G, out_xyz, out_feat);
}

// Round 8
// 618.226 us; speedup vs baseline: 1.1496x; 1.1176x over previous
//
#include <hip/hip_runtime.h>

#define BATCH 8
#define LFRM  6
#define NP    2048
#define MP    1024
#define CIN   64
#define MIDC  128
#define OUTC  256
#define TKM   384
#define KNN   32
#define RAD2  0.25f

#define FPS_BLOCKS (BATCH * LFRM)
#define FT_BLOCKS  (BATCH * LFRM * (NP / 64))
#define WFS 132   // wfT row stride: 16B-aligned rows (528B) for b128 reads

typedef float f2 __attribute__((ext_vector_type(2)));
typedef float f32x4 __attribute__((ext_vector_type(4)));
typedef _Float16 f16x8 __attribute__((ext_vector_type(8)));
typedef _Float16 f16x4 __attribute__((ext_vector_type(4)));

// LDS union: fps needs 32.9KB; ftrans needs ~51.3KB.
union SharedU {
  struct {
    float4 pts[NP];                    // 32 KB, [x,y,z,pad]
    unsigned long long wk[2][4];       // parity-double-buffered wave keys
  } fps;
  struct {
    float ftile[CIN][64];              // 16 KB
    float wfT[CIN][WFS];               // 33 KB  [c][o], 16B-aligned rows
    float xt[64], yt[64], zt[64];      // point coords of this tile
    float wdl[MIDC * 3];               // w_d staged
  } ft;
};

__device__ __forceinline__ uint64_t kmax64(uint64_t a, uint64_t b) {
  return a > b ? a : b;
}
template <int CTRL>
__device__ __forceinline__ uint64_t key_dpp(uint64_t k) {
  int lo = __builtin_amdgcn_update_dpp((int)(uint32_t)k, (int)(uint32_t)k,
                                       CTRL, 0xF, 0xF, false);
  int hi = __builtin_amdgcn_update_dpp((int)(uint32_t)(k >> 32),
                                       (int)(uint32_t)(k >> 32),
                                       CTRL, 0xF, 0xF, false);
  return ((uint64_t)(uint32_t)hi << 32) | (uint32_t)lo;
}

// ---------------------------------------------------------------------------
// FPS: the round-2 structure (fastest measured: 1027 cyc/iter), with ONE
// change: the two LDS-pipe cross-lane steps (swz16 / shfl_x32) are replaced
// by row_bcast15 + row_bcast31 DPP (pure VALU); lane 63 then holds the wave
// max and publishes. Key = (f32bits(dist)<<32) | ~idx; max-key == numpy
// first-occurrence argmax (validated rounds 1-7).
// ---------------------------------------------------------------------------
__device__ __forceinline__ void fps_path(const float* __restrict__ xyzs,
                                         float* __restrict__ out_xyz,
                                         SharedU* sh) {
#pragma clang fp contract(off)
  const int bt = blockIdx.x;              // b*6 + frame
  const int tid = threadIdx.x;
  const int lane = tid & 63, wv = tid >> 6;
  const float* src = xyzs + (size_t)bt * NP * 3;

  for (int q = tid; q < NP; q += 256)
    sh->fps.pts[q] = make_float4(src[q * 3 + 0], src[q * 3 + 1], src[q * 3 + 2], 0.f);
  __syncthreads();

  // wave wv owns slots [wv*8, wv*8+8); point p = slot*64 + lane
  f2 px[4], py[4], pz[4], dist[4];
#pragma unroll
  for (int u = 0; u < 4; ++u) {
    float4 a = sh->fps.pts[(wv * 8 + 2 * u) * 64 + lane];
    float4 b = sh->fps.pts[(wv * 8 + 2 * u + 1) * 64 + lane];
    px[u] = f2{a.x, b.x};
    py[u] = f2{a.y, b.y};
    pz[u] = f2{a.z, b.z};
    dist[u] = f2{1e10f, 1e10f};
  }

  float4 p0 = sh->fps.pts[0];
  float fx = p0.x, fy = p0.y, fz = p0.z;  // far = 0 initially
  float* dst = out_xyz + (size_t)bt * MP * 3;

  for (int it = 0; it < MP; ++it) {
    if (tid == 0) {                       // emit current far point
      dst[it * 3 + 0] = fx;
      dst[it * 3 + 1] = fy;
      dst[it * 3 + 2] = fz;
    }
    const f2 fx2 = {fx, fx}, fy2 = {fy, fy}, fz2 = {fz, fz};
    float bv = -1.0f;
    int bsu = 0;
#pragma unroll
    for (int u = 0; u < 4; ++u) {
      f2 dx = px[u] - fx2;
      f2 dy = py[u] - fy2;
      f2 dz = pz[u] - fz2;
      f2 m = dx * dx;                     // contract off: ((dx^2+dy^2)+dz^2)
      m = m + dy * dy;
      m = m + dz * dz;
      f2 nd = __builtin_elementwise_min(dist[u], m);
      dist[u] = nd;
      bool cx = nd.x > bv;                // first-occurrence: strict >
      bv = cx ? nd.x : bv;
      bsu = cx ? 2 * u : bsu;
      bool cy = nd.y > bv;
      bv = cy ? nd.y : bv;
      bsu = cy ? 2 * u + 1 : bsu;
    }
    const uint32_t p = (uint32_t)(((wv * 8 + bsu) << 6) | lane);
    uint64_t key = ((uint64_t)__float_as_uint(bv) << 32) | (uint32_t)(~p);
    key = kmax64(key, key_dpp<0x121>(key));   // row_ror:1
    key = kmax64(key, key_dpp<0x122>(key));   // row_ror:2
    key = kmax64(key, key_dpp<0x124>(key));   // row_ror:4
    key = kmax64(key, key_dpp<0x128>(key));   // row_ror:8  -> row max
    key = kmax64(key, key_dpp<0x142>(key));   // row_bcast15
    key = kmax64(key, key_dpp<0x143>(key));   // row_bcast31: lane63 = wave max

    const int par = it & 1;
    if (lane == 63) sh->fps.wk[par][wv] = key;
    __syncthreads();
    uint64_t k0 = kmax64(sh->fps.wk[par][0], sh->fps.wk[par][1]);
    uint64_t k1 = kmax64(sh->fps.wk[par][2], sh->fps.wk[par][3]);
    uint64_t kg = kmax64(k0, k1);
    const uint32_t wp = ~(uint32_t)kg;        // winner point index
    float4 w = sh->fps.pts[wp];               // uniform -> broadcast read
    fx = w.x; fy = w.y; fz = w.z;
  }
}

// ---------------------------------------------------------------------------
// ftrans: G[b,l,n,o] = sum_c w_f[o,c]*features[b,l,c,n] + w_d[o]·xyz[b,l,n]
// Register-blocked 4o x 8n per thread: per c, 1 ds_read_b128 (w quad) +
// 2 broadcast ds_read_b128 (ftile) + 32 FMA  (was 2 ds_read_b32 per FMA).
// ---------------------------------------------------------------------------
__device__ __forceinline__ void ftrans_path(const float* __restrict__ features,
                                            const float* __restrict__ w_f,
                                            const float* __restrict__ w_d,
                                            const float* __restrict__ xyzs,
                                            float* __restrict__ G,
                                            SharedU* sh) {
  const int blk = blockIdx.x - FPS_BLOCKS;
  const int ntile = blk & 31;             // N/64 tiles
  const int bl = blk >> 5;                // b*L + l
  const int tid = threadIdx.x;

  const float* fsrc = features + (size_t)bl * CIN * NP + (size_t)ntile * 64;
  for (int idx = tid; idx < CIN * 64; idx += 256) {
    int c = idx >> 6, n = idx & 63;
    sh->ft.ftile[c][n] = fsrc[(size_t)c * NP + n];
  }
  for (int idx = tid; idx < CIN * MIDC; idx += 256) {
    int c = idx & 63, o = idx >> 6;       // coalesced w_f row reads
    sh->ft.wfT[c][o] = w_f[o * CIN + c];
  }
  if (tid < 64) {
    const float* xs = xyzs + ((size_t)bl * NP + (size_t)ntile * 64 + tid) * 3;
    sh->ft.xt[tid] = xs[0];
    sh->ft.yt[tid] = xs[1];
    sh->ft.zt[tid] = xs[2];
  }
  for (int idx = tid; idx < MIDC * 3; idx += 256) sh->ft.wdl[idx] = w_d[idx];
  __syncthreads();

  const int op = tid & 31;                // o base = op*4 (coalesced stores)
  const int ng = tid >> 5;                // n base = ng*8 (broadcast ftile)
  const int ob = op * 4;
  const int nb = ng * 8;

  float acc[4][8];                        // all index loops fully unrolled
#pragma unroll
  for (int oo = 0; oo < 4; ++oo) {
    const float w0 = sh->ft.wdl[(ob + oo) * 3 + 0];
    const float w1 = sh->ft.wdl[(ob + oo) * 3 + 1];
    const float w2 = sh->ft.wdl[(ob + oo) * 3 + 2];
#pragma unroll
    for (int j = 0; j < 8; ++j)
      acc[oo][j] = w0 * sh->ft.xt[nb + j] + w1 * sh->ft.yt[nb + j] +
                   w2 * sh->ft.zt[nb + j];
  }

#pragma unroll 4
  for (int c = 0; c < CIN; ++c) {
    const float4 wq = *(const float4*)&sh->ft.wfT[c][ob];
    const float4 fA = *(const float4*)&sh->ft.ftile[c][nb];
    const float4 fB = *(const float4*)&sh->ft.ftile[c][nb + 4];
    const float wo[4] = {wq.x, wq.y, wq.z, wq.w};
    const float fv[8] = {fA.x, fA.y, fA.z, fA.w, fB.x, fB.y, fB.z, fB.w};
#pragma unroll
    for (int oo = 0; oo < 4; ++oo)
#pragma unroll
      for (int j = 0; j < 8; ++j)
        acc[oo][j] += wo[oo] * fv[j];
  }

  float* dstp = G + ((size_t)bl * NP + (size_t)ntile * 64) * MIDC;
#pragma unroll
  for (int j = 0; j < 8; ++j) {
    float4 v = make_float4(acc[0][j], acc[1][j], acc[2][j], acc[3][j]);
    *(float4*)&dstp[(size_t)(nb + j) * MIDC + ob] = v;
  }
}

__global__ __launch_bounds__(256, 1) void fps_ftrans_kernel(
    const float* __restrict__ xyzs, const float* __restrict__ features,
    const float* __restrict__ w_f, const float* __restrict__ w_d,
    float* __restrict__ out_xyz, float* __restrict__ G) {
  __shared__ SharedU sh;
  if (blockIdx.x < FPS_BLOCKS) {
    fps_path(xyzs, out_xyz, &sh);
    return;
  }
  ftrans_path(features, w_f, w_d, xyzs, G, &sh);
}

// ---------------------------------------------------------------------------
// pst_main: ball query + gathered max-pool of G + fp16 MFMA w_t GEMM.
// (unchanged: measured ~123-153 us)
// ---------------------------------------------------------------------------
#define PSTR 392   // fp16 K-stride: 2-way banks on B-frag ds_read_b128

__global__ __launch_bounds__(256) void pst_main(const float* __restrict__ xyzs,
                                                const float* __restrict__ w_d,
                                                const float* __restrict__ w_t,
                                                const float* __restrict__ G,
                                                const float* __restrict__ anchors,
                                                float* __restrict__ out_feat) {
  __shared__ float pxyz[NP * 3];              // 24 KB frame xyz
  __shared__ _Float16 sfp16[32][PSTR];        // 24.5 KB sf (all 3 slices), fp16
  __shared__ unsigned short nidx[32][KNN];    // 2 KB
  __shared__ float anc[32][3];

  const int blk = blockIdx.x;
  const int mt = blk & 31;                // M/32 tiles
  const int bt = blk >> 5;                // b*6 + (t-1)
  const int b = bt / LFRM;
  const int t = bt % LFRM + 1;            // padded time index, 1..6
  const int tid = threadIdx.x;

  const float* asrc = anchors + ((size_t)bt * MP + (size_t)mt * 32) * 3;
  if (tid < 96) anc[tid / 3][tid % 3] = asrc[tid];
  __syncthreads();

  const int al = tid >> 3;                // anchor 0..31
  const int j = tid & 7;                  // 0..7 within anchor group
  const float ax = anc[al][0], ay = anc[al][1], az = anc[al][2];

  float wda[16];
#pragma unroll
  for (int c4 = 0; c4 < 4; ++c4)
#pragma unroll
    for (int r = 0; r < 4; ++r) {
      int o = c4 * 32 + j * 4 + r;
      wda[c4 * 4 + r] = w_d[o * 3 + 0] * ax + w_d[o * 3 + 1] * ay +
                        w_d[o * 3 + 2] * az;
    }

  const int lane = tid & 63, wv = tid >> 6;

  for (int ii = 0; ii < 3; ++ii) {
    const int i = t - 1 + ii;             // padded frame 0..7
    float mg[16];
#pragma unroll
    for (int u = 0; u < 16; ++u) mg[u] = 0.f;   // pad frame: maxG := 0

    if (i != 0 && i != LFRM + 1) {
      const int f2i = i - 1;
      const float* fxyz = xyzs + (size_t)(b * LFRM + f2i) * NP * 3;
      __syncthreads();                    // prior ball-query reads done
      for (int q = tid; q < NP * 3; q += 256) pxyz[q] = fxyz[q];
      __syncthreads();

      // ---- ball query: first KNN in-radius indices, in index order ----
      for (int aa = 0; aa < 8; ++aa) {
        const int a = wv * 8 + aa;
        const float qx = anc[a][0], qy = anc[a][1], qz = anc[a][2];
        int total = 0;
        int fillidx = 0;
        for (int ch = 0; ch < NP / 64; ++ch) {
          const int p = ch * 64 + lane;
          float d2;
          {
#pragma clang fp contract(off)
            float dx = qx - pxyz[p * 3 + 0];
            float dy = qy - pxyz[p * 3 + 1];
            float dz = qz - pxyz[p * 3 + 2];
            d2 = dx * dx + dy * dy + dz * dz;
          }
          const bool inb = d2 < RAD2;
          const unsigned long long mk = __ballot(inb);
          if (mk != 0ull && total == 0)
            fillidx = ch * 64 + (int)__builtin_ctzll(mk);
          const int before = (int)__builtin_popcountll(mk & ((1ull << lane) - 1ull));
          const int slot = total + before;
          if (inb && slot < KNN) nidx[a][slot] = (unsigned short)p;
          total += (int)__builtin_popcountll(mk);
          if (total >= KNN) break;        // uniform across wave
        }
        const int nf = total < KNN ? total : KNN;
        if (lane < KNN - nf) nidx[a][nf + lane] = (unsigned short)fillidx;
      }
      __syncthreads();

      // ---- mid: pure max over gathered G rows ----
      const float* gf = G + (size_t)(b * LFRM + f2i) * NP * MIDC;
#pragma unroll
      for (int u = 0; u < 16; ++u) mg[u] = -1e30f;
      for (int k = 0; k < KNN; ++k) {
        const int p = nidx[al][k];
        const float4* row = (const float4*)(gf + (size_t)p * MIDC);
#pragma unroll
        for (int c4 = 0; c4 < 4; ++c4) {
          float4 v = row[c4 * 8 + j];
          mg[c4 * 4 + 0] = fmaxf(mg[c4 * 4 + 0], v.x);
          mg[c4 * 4 + 1] = fmaxf(mg[c4 * 4 + 1], v.y);
          mg[c4 * 4 + 2] = fmaxf(mg[c4 * 4 + 2], v.z);
          mg[c4 * 4 + 3] = fmaxf(mg[c4 * 4 + 3], v.w);
        }
      }
    }

    // sf = relu(maxG - wda) -> fp16, packed 4-wide writes
#pragma unroll
    for (int c4 = 0; c4 < 4; ++c4) {
      f16x4 h;
#pragma unroll
      for (int r = 0; r < 4; ++r)
        h[r] = (_Float16)fmaxf(mg[c4 * 4 + r] - wda[c4 * 4 + r], 0.f);
      *(f16x4*)&sfp16[al][ii * MIDC + c4 * 32 + j * 4] = h;
    }
  }
  __syncthreads();

  // ---- GEMM: wave wv owns M-tiles wv*4..wv*4+3 (out-ch), N-tiles 0..1 ----
  const int l16 = lane & 15, lq = lane >> 4;
  f32x4 accm[4][2];
#pragma unroll
  for (int q = 0; q < 4; ++q)
#pragma unroll
    for (int n2 = 0; n2 < 2; ++n2) accm[q][n2] = f32x4{0.f, 0.f, 0.f, 0.f};

  for (int kc = 0; kc < TKM / 32; ++kc) {
    f16x8 bfr[2];
#pragma unroll
    for (int n2 = 0; n2 < 2; ++n2)
      bfr[n2] = *(const f16x8*)&sfp16[n2 * 16 + l16][kc * 32 + lq * 8];
#pragma unroll
    for (int q = 0; q < 4; ++q) {
      const int row = (wv * 4 + q) * 16 + l16;
      const float4* ap = (const float4*)(w_t + (size_t)row * TKM + kc * 32 + lq * 8);
      float4 a0 = ap[0], a1 = ap[1];
      f16x8 afr;
      afr[0] = (_Float16)a0.x; afr[1] = (_Float16)a0.y;
      afr[2] = (_Float16)a0.z; afr[3] = (_Float16)a0.w;
      afr[4] = (_Float16)a1.x; afr[5] = (_Float16)a1.y;
      afr[6] = (_Float16)a1.z; afr[7] = (_Float16)a1.w;
      accm[q][0] = __builtin_amdgcn_mfma_f32_16x16x32_f16(afr, bfr[0], accm[q][0], 0, 0, 0);
      accm[q][1] = __builtin_amdgcn_mfma_f32_16x16x32_f16(afr, bfr[1], accm[q][1], 0, 0, 0);
    }
  }

  // epilogue: D row = out-ch offset lq*4+r, col = anchor l16 (m89 layout)
  float* ob = out_feat + (size_t)bt * OUTC * MP + (size_t)mt * 32;
#pragma unroll
  for (int q = 0; q < 4; ++q) {
    const int orow = (wv * 4 + q) * 16 + lq * 4;
#pragma unroll
    for (int n2 = 0; n2 < 2; ++n2)
#pragma unroll
      for (int r = 0; r < 4; ++r)
        ob[(size_t)(orow + r) * MP + n2 * 16 + l16] = accm[q][n2][r];
  }
}

// ---------------------------------------------------------------------------
extern "C" void kernel_launch(void* const* d_in, const int* in_sizes, int n_in,
                              void* d_out, int out_size, void* d_ws, size_t ws_size,
                              hipStream_t stream) {
  const float* xyzs = (const float*)d_in[0];
  const float* features = (const float*)d_in[1];
  const float* w_d = (const float*)d_in[2];
  const float* w_f = (const float*)d_in[3];
  const float* w_t = (const float*)d_in[4];

  float* out = (float*)d_out;
  float* out_xyz = out;                                        // (B,6,M,3)
  float* out_feat = out + (size_t)BATCH * LFRM * MP * 3;       // (B,6,256,M)
  float* G = (float*)d_ws;                                     // (B,L,N,128)

  hipLaunchKernelGGL(fps_ftrans_kernel, dim3(FPS_BLOCKS + FT_BLOCKS), dim3(256),
                     0, stream, xyzs, features, w_f, w_d, out_xyz, G);
  hipLaunchKernelGGL(pst_main, dim3(BATCH * LFRM * (MP / 32)), dim3(256), 0,
                     stream, xyzs, w_d, w_t, G, out_xyz, out_feat);
}